// Round 7
// baseline (164.015 us; speedup 1.0000x reference)
//
#include <hip/hip_runtime.h>
#include <hip/hip_fp16.h>

#define NN 50000      // nodes
#define FF 128        // features
#define NE 800000     // edges
#define NT 5000       // train ids
#define NF (NN * FF)  // 6,400,000
#define CAP 64        // bucket capacity per row (max realized degree ~38)
#define PADVAL 0x0000C350u  // col=50000 (zero Q row), f16 adj = 0

typedef __attribute__((ext_vector_type(8))) short bf16x8;
typedef __attribute__((ext_vector_type(4))) float f32x4;
typedef __attribute__((ext_vector_type(4))) unsigned u32x4;
typedef __attribute__((ext_vector_type(2))) unsigned u32x2;
typedef __attribute__((ext_vector_type(4))) int i32x4;

__device__ __forceinline__ unsigned bf16_rne(float f) {
    unsigned u = __float_as_uint(f);
    return (u + 0x7FFFu + ((u >> 16) & 1u)) >> 16;
}

// ---------------- zero counts/flags + pad eca buckets ----------------
__global__ void k_zero(int* __restrict__ counts, int* __restrict__ flags,
                       unsigned* __restrict__ eca) {
    int i = blockIdx.x * blockDim.x + threadIdx.x;
    if (i < (NN * CAP) / 4) {
        u32x4 v = {PADVAL, PADVAL, PADVAL, PADVAL};
        __builtin_nontemporal_store(v, reinterpret_cast<u32x4*>(eca) + i);
    }
    if (i < NN) { counts[i] = 0; flags[i] = 0; }
}

__global__ void k_flags(const int* __restrict__ ids, int* __restrict__ flags) {
    int i = blockIdx.x * blockDim.x + threadIdx.x;
    if (i < NT) flags[ids[i]] = 1;
}

// ---------------- pack Q[n][f] = (bf16(me) | bf16(me*x)<<16); row NN = 0 ----
__global__ void k_pack(const float* __restrict__ M, const float* __restrict__ x,
                       const int* __restrict__ flags, unsigned* __restrict__ Q) {
    int i4 = blockIdx.x * blockDim.x + threadIdx.x;  // one float4 (4 features)
    if (i4 >= NF / 4 + FF / 4) return;
    u32x4* Q4 = reinterpret_cast<u32x4*>(Q);
    if (i4 >= NF / 4) {  // zero pad row (node NN)
        u32x4 z = {0, 0, 0, 0};
        Q4[i4] = z;
        return;
    }
    int node = (i4 * 4) >> 7;
    int trn = flags[node];
    f32x4 m = __builtin_nontemporal_load(reinterpret_cast<const f32x4*>(M) + i4);
    f32x4 xv = __builtin_nontemporal_load(reinterpret_cast<const f32x4*>(x) + i4);
    float me0 = trn ? 1.0f : 1.0f / (1.0f + __expf(-m.x));
    float me1 = trn ? 1.0f : 1.0f / (1.0f + __expf(-m.y));
    float me2 = trn ? 1.0f : 1.0f / (1.0f + __expf(-m.z));
    float me3 = trn ? 1.0f : 1.0f / (1.0f + __expf(-m.w));
    u32x4 q;
    q.x = bf16_rne(me0) | (bf16_rne(me0 * xv.x) << 16);
    q.y = bf16_rne(me1) | (bf16_rne(me1 * xv.y) << 16);
    q.z = bf16_rne(me2) | (bf16_rne(me2 * xv.z) << 16);
    q.w = bf16_rne(me3) | (bf16_rne(me3 * xv.w) << 16);
    Q4[i4] = q;
}

// ---------------- bucket fill: 4 edges/thread, independent atomic chains ---
__global__ __launch_bounds__(256)
void k_fillb(const int* __restrict__ rows, const int* __restrict__ cols,
             const float* __restrict__ adj, int* __restrict__ counts,
             unsigned* __restrict__ eca) {
    int i = blockIdx.x * blockDim.x + threadIdx.x;
    if (i >= NE / 4) return;
    i32x4 r = __builtin_nontemporal_load(reinterpret_cast<const i32x4*>(rows) + i);
    i32x4 c = __builtin_nontemporal_load(reinterpret_cast<const i32x4*>(cols) + i);
    f32x4 a = __builtin_nontemporal_load(reinterpret_cast<const f32x4*>(adj) + i);
    // 4 independent atomic chains in flight
    int p0 = atomicAdd(&counts[r.x], 1);
    int p1 = atomicAdd(&counts[r.y], 1);
    int p2 = atomicAdd(&counts[r.z], 1);
    int p3 = atomicAdd(&counts[r.w], 1);
    unsigned h0 = (unsigned)__half_as_ushort(__float2half_rn(a.x));
    unsigned h1 = (unsigned)__half_as_ushort(__float2half_rn(a.y));
    unsigned h2 = (unsigned)__half_as_ushort(__float2half_rn(a.z));
    unsigned h3 = (unsigned)__half_as_ushort(__float2half_rn(a.w));
    if (p0 < CAP)
        __builtin_nontemporal_store((unsigned)c.x | (h0 << 16), &eca[r.x * CAP + p0]);
    if (p1 < CAP)
        __builtin_nontemporal_store((unsigned)c.y | (h1 << 16), &eca[r.y * CAP + p1]);
    if (p2 < CAP)
        __builtin_nontemporal_store((unsigned)c.z | (h2 << 16), &eca[r.z * CAP + p2]);
    if (p3 < CAP)
        __builtin_nontemporal_store((unsigned)c.w | (h3 << 16), &eca[r.w * CAP + p3]);
}

// ---------------- gather: one wave per 4 rows, branch-free padded loop -----
__global__ __launch_bounds__(256)
void k_gather(const int* __restrict__ counts, const unsigned* __restrict__ eca,
              const unsigned* __restrict__ Q, unsigned* __restrict__ Hnb) {
    int t = blockIdx.x * blockDim.x + threadIdx.x;
    int wv = t >> 6;
    int lane = t & 63;
    int r0 = wv * 4;              // NN % 4 == 0
    if (r0 >= NN) return;
    int dmax = 0;
#pragma unroll
    for (int s = 0; s < 4; ++s) dmax = max(dmax, min(counts[r0 + s], CAP));
    int nch = (dmax + 3) >> 2;
    const u32x2* Q2 = reinterpret_cast<const u32x2*>(Q);
    float d[4][2], h[4][2];
#pragma unroll
    for (int s = 0; s < 4; ++s) { d[s][0] = d[s][1] = h[s][0] = h[s][1] = 0.f; }
    for (int c = 0; c < nch; ++c) {
        u32x4 E[4];
#pragma unroll
        for (int s = 0; s < 4; ++s)
            E[s] = __builtin_nontemporal_load(
                reinterpret_cast<const u32x4*>(eca + (size_t)(r0 + s) * CAP) + c);
#pragma unroll
        for (int i = 0; i < 4; ++i) {
#pragma unroll
            for (int s = 0; s < 4; ++s) {
                unsigned e = (i == 0) ? E[s].x : (i == 1) ? E[s].y
                           : (i == 2) ? E[s].z : E[s].w;
                unsigned col = e & 0xFFFFu;
                float a = __half2float(__ushort_as_half((unsigned short)(e >> 16)));
                u32x2 q = Q2[(int)col * 64 + lane];  // pad col -> zero row
                d[s][0] += __uint_as_float(q.x << 16);
                d[s][1] += __uint_as_float(q.y << 16);
                h[s][0] += a * __uint_as_float(q.x & 0xFFFF0000u);
                h[s][1] += a * __uint_as_float(q.y & 0xFFFF0000u);
            }
        }
    }
#pragma unroll
    for (int s = 0; s < 4; ++s) {
        float o0 = (d[s][0] == 0.f) ? 0.f : h[s][0] / d[s][0];
        float o1 = (d[s][1] == 0.f) ? 0.f : h[s][1] / d[s][1];
        __builtin_nontemporal_store(bf16_rne(o0) | (bf16_rne(o1) << 16),
                                    &Hnb[(r0 + s) * 64 + lane]);
    }
}

// ---------------- out = elu(Hn @ W) via MFMA bf16 ----------------
__global__ __launch_bounds__(256)
void k_gemm(const unsigned* __restrict__ Hnb, const float* __restrict__ W,
            float* __restrict__ out) {
    __shared__ short Wb[128 * 128];  // 32KB: [((t*4+ks)*64 + l)*8 + j]
    int tid = threadIdx.x;

    // stage W -> bf16 swizzled. combo c = (lh<<9)|(ks<<7)|(t<<4)|nl
#pragma unroll
    for (int i = 0; i < 8; ++i) {
        int c = tid + i * 256;            // 0..2047
        int nl = c & 15;
        int t8 = (c >> 4) & 7;
        int ks = (c >> 7) & 3;
        int lh = (c >> 9) & 3;
        int l = nl | (lh << 4);
        int n = t8 * 16 + nl;
        int k0 = ks * 32 + lh * 8;
        short v[8];
#pragma unroll
        for (int j = 0; j < 8; ++j)
            v[j] = (short)bf16_rne(W[(k0 + j) * 128 + n]);
        *reinterpret_cast<bf16x8*>(&Wb[((t8 * 4 + ks) * 64 + l) * 8]) =
            *reinterpret_cast<bf16x8*>(v);
    }
    __syncthreads();

    int wave = tid >> 6, lane = tid & 63;
    int r0 = blockIdx.x * 64 + wave * 16;
    int mrow = lane & 15;
    int kg = lane >> 4;
    int arow = min(r0 + mrow, NN - 1);
    const u32x4* H4 = reinterpret_cast<const u32x4*>(Hnb);

    bf16x8 a[4];
#pragma unroll
    for (int ks = 0; ks < 4; ++ks) {
        u32x4 v = H4[(size_t)arow * 16 + ks * 4 + kg];
        a[ks] = *reinterpret_cast<bf16x8*>(&v);
    }

    f32x4 acc[8];
#pragma unroll
    for (int t8 = 0; t8 < 8; ++t8) acc[t8] = (f32x4){0.f, 0.f, 0.f, 0.f};

#pragma unroll
    for (int t8 = 0; t8 < 8; ++t8) {
#pragma unroll
        for (int ks = 0; ks < 4; ++ks) {
            bf16x8 b = *reinterpret_cast<const bf16x8*>(
                &Wb[((t8 * 4 + ks) * 64 + lane) * 8]);
            acc[t8] = __builtin_amdgcn_mfma_f32_16x16x32_bf16(a[ks], b, acc[t8], 0, 0, 0);
        }
    }

    // C/D layout: col = lane&15, row = (lane>>4)*4 + reg  [m89-verified]
    int colb = lane & 15;
    int rsub = (lane >> 4) * 4;
#pragma unroll
    for (int t8 = 0; t8 < 8; ++t8) {
#pragma unroll
        for (int rg = 0; rg < 4; ++rg) {
            int row = r0 + rsub + rg;
            if (row < NN) {
                float v = acc[t8][rg];
                float o = (v > 0.f) ? v : (__expf(v) - 1.0f);
                __builtin_nontemporal_store(o, &out[(size_t)row * 128 + t8 * 16 + colb]);
            }
        }
    }
}

// ================= fallback (atomic scatter) if ws is small =================
__global__ void k_init_fb(float* __restrict__ denomH, int* __restrict__ flags) {
    int i = blockIdx.x * blockDim.x + threadIdx.x;
    const int total4 = (2 * NF) / 4;
    if (i < total4)
        reinterpret_cast<float4*>(denomH)[i] = make_float4(0.f, 0.f, 0.f, 0.f);
    if (i < NN) flags[i] = 0;
}

__global__ __launch_bounds__(256)
void k_edge_fb(const int* __restrict__ rows, const int* __restrict__ cols,
               const float* __restrict__ adj, const float* __restrict__ M,
               const int* __restrict__ flags, const float* __restrict__ x,
               float* __restrict__ denom, float* __restrict__ H) {
    int t = blockIdx.x * blockDim.x + threadIdx.x;
    int e = t >> 6;
    int lane = t & 63;
    if (e >= NE) return;
    int r = rows[e], c = cols[e];
    float a = adj[e];
#pragma unroll
    for (int i = 0; i < 2; ++i) {
        int f = lane + i * 64;
        float m = M[c * FF + f];
        float me = flags[c] ? 1.0f : 1.0f / (1.0f + __expf(-m));
        float xv = x[c * FF + f];
        unsafeAtomicAdd(&denom[r * FF + f], me);
        unsafeAtomicAdd(&H[r * FF + f], a * me * xv);
    }
}

__global__ __launch_bounds__(256)
void k_norm_fb(const float* __restrict__ H, const float* __restrict__ denom,
               float* __restrict__ Hn) {
    int i = blockIdx.x * blockDim.x + threadIdx.x;
    if (i >= NF) return;
    float d = denom[i];
    Hn[i] = (d == 0.f) ? 0.f : H[i] / d;
}

__global__ __launch_bounds__(256)
void k_gemm_fb(const float* __restrict__ Hn, const float* __restrict__ W,
               float* __restrict__ out) {
    __shared__ float Ws[128][128];
    __shared__ float Hs[32][128];
    int tid = threadIdx.x;
    const float4* W4 = reinterpret_cast<const float4*>(W);
    float4* Ws4 = reinterpret_cast<float4*>(&Ws[0][0]);
#pragma unroll
    for (int i = 0; i < 16; ++i) Ws4[tid + i * 256] = W4[tid + i * 256];
    int r0 = blockIdx.x * 32;
    const float4* H4 = reinterpret_cast<const float4*>(Hn);
    float4* Hs4 = reinterpret_cast<float4*>(&Hs[0][0]);
#pragma unroll
    for (int i = 0; i < 4; ++i) {
        int m = tid + i * 256;
        int r = m >> 5, k4 = m & 31;
        int row = r0 + r;
        Hs4[m] = (row < NN) ? H4[row * 32 + k4] : make_float4(0.f, 0.f, 0.f, 0.f);
    }
    __syncthreads();
    int c = tid & 127, rg = tid >> 7;
    float acc[16];
#pragma unroll
    for (int i = 0; i < 16; ++i) acc[i] = 0.f;
    for (int k = 0; k < 128; k += 4) {
        float w0 = Ws[k][c], w1 = Ws[k + 1][c], w2 = Ws[k + 2][c], w3 = Ws[k + 3][c];
#pragma unroll
        for (int i = 0; i < 16; ++i) {
            float4 h = *reinterpret_cast<const float4*>(&Hs[rg * 16 + i][k]);
            acc[i] += h.x * w0 + h.y * w1 + h.z * w2 + h.w * w3;
        }
    }
#pragma unroll
    for (int i = 0; i < 16; ++i) {
        int row = r0 + rg * 16 + i;
        if (row < NN) {
            float v = acc[i];
            out[row * 128 + c] = (v > 0.f) ? v : (__expf(v) - 1.0f);
        }
    }
}

extern "C" void kernel_launch(void* const* d_in, const int* in_sizes, int n_in,
                              void* d_out, int out_size, void* d_ws, size_t ws_size,
                              hipStream_t stream) {
    const float* x     = (const float*)d_in[0];
    const int*   erows = (const int*)d_in[1];
    const int*   ecols = (const int*)d_in[2];
    const float* adj   = (const float*)d_in[3];
    const int*   train = (const int*)d_in[4];
    const float* M     = (const float*)d_in[5];
    const float* W     = (const float*)d_in[6];
    float* out = (float*)d_out;
    float* ws  = (float*)d_ws;

    // ws layout (4-byte units):
    // [Q: NF+FF (incl zero pad row)][Hnb: NF/2][eca: NN*CAP][counts NN][flags NN]
    size_t fo = 0;
    unsigned* Q   = (unsigned*)(ws + fo); fo += NF + FF;
    unsigned* Hnb = (unsigned*)(ws + fo); fo += NF / 2;
    unsigned* eca = (unsigned*)(ws + fo); fo += (size_t)NN * CAP;
    int* counts   = (int*)(ws + fo); fo += NN;
    int* flags    = (int*)(ws + fo); fo += NN;
    const size_t need = fo * 4;  // ~51.7 MB

    if (ws_size >= need) {
        k_zero<<<((NN * CAP / 4) + 255) / 256, 256, 0, stream>>>(counts, flags, eca);
        k_flags<<<(NT + 255) / 256, 256, 0, stream>>>(train, flags);
        k_pack<<<(NF / 4 + FF / 4 + 255) / 256, 256, 0, stream>>>(M, x, flags, Q);
        k_fillb<<<(NE / 4 + 255) / 256, 256, 0, stream>>>(erows, ecols, adj, counts, eca);
        k_gather<<<((NN / 4) * 64 + 255) / 256, 256, 0, stream>>>(counts, eca, Q, Hnb);
        k_gemm<<<(NN + 63) / 64, 256, 0, stream>>>(Hnb, W, out);
    } else {
        float* denom = ws;
        float* H     = ws + NF;
        int* flags_fb = (int*)(ws + 2 * (size_t)NF);
        k_init_fb<<<(2 * NF / 4 + 255) / 256, 256, 0, stream>>>(denom, flags_fb);
        k_flags<<<(NT + 255) / 256, 256, 0, stream>>>(train, flags_fb);
        k_edge_fb<<<((size_t)NE * 64 + 255) / 256, 256, 0, stream>>>(
            erows, ecols, adj, M, flags_fb, x, denom, H);
        k_norm_fb<<<(NF + 255) / 256, 256, 0, stream>>>(H, denom, denom);
        k_gemm_fb<<<(NN + 31) / 32, 256, 0, stream>>>(denom, W, out);
    }
}

// Round 8
// 154.334 us; speedup vs baseline: 1.0627x; 1.0627x over previous
//
#include <hip/hip_runtime.h>
#include <hip/hip_fp16.h>

#define NN 50000      // nodes
#define FF 128        // features
#define NE 800000     // edges
#define NT 5000       // train ids
#define NF (NN * FF)  // 6,400,000
#define CAP 64        // bucket capacity per row (max realized degree ~38)
#define CSTR 16       // counter stride (ints): 1 counter per 64B line
#define PADVAL 0x0000C350u  // col=50000 (zero Q row), f16 adj = 0

typedef __attribute__((ext_vector_type(8))) short bf16x8;
typedef __attribute__((ext_vector_type(4))) float f32x4;
typedef __attribute__((ext_vector_type(4))) unsigned u32x4;
typedef __attribute__((ext_vector_type(2))) unsigned u32x2;
typedef __attribute__((ext_vector_type(4))) int i32x4;

__device__ __forceinline__ unsigned bf16_rne(float f) {
    unsigned u = __float_as_uint(f);
    return (u + 0x7FFFu + ((u >> 16) & 1u)) >> 16;
}

// ---------- zero padded counts + flags + pad eca buckets ----------
__global__ void k_zero(int* __restrict__ counts, int* __restrict__ flags,
                       unsigned* __restrict__ eca) {
    int i = blockIdx.x * blockDim.x + threadIdx.x;
    if (i < (NN * CAP) / 4) {
        u32x4 v = {PADVAL, PADVAL, PADVAL, PADVAL};
        __builtin_nontemporal_store(v, reinterpret_cast<u32x4*>(eca) + i);
    }
    if (i < (NN * CSTR) / 4) {
        i32x4 z = {0, 0, 0, 0};
        reinterpret_cast<i32x4*>(counts)[i] = z;
    }
    if (i < NN) flags[i] = 0;
}

__global__ void k_flags(const int* __restrict__ ids, int* __restrict__ flags) {
    int i = blockIdx.x * blockDim.x + threadIdx.x;
    if (i < NT) flags[ids[i]] = 1;
}

// ---------- pack Q[n][f] = (bf16(me) | bf16(me*x)<<16); row NN = 0 ----------
__global__ void k_pack(const float* __restrict__ M, const float* __restrict__ x,
                       const int* __restrict__ flags, unsigned* __restrict__ Q) {
    int i4 = blockIdx.x * blockDim.x + threadIdx.x;  // one float4 (4 features)
    if (i4 >= NF / 4 + FF / 4) return;
    u32x4* Q4 = reinterpret_cast<u32x4*>(Q);
    if (i4 >= NF / 4) {  // zero pad row (node NN)
        u32x4 z = {0, 0, 0, 0};
        Q4[i4] = z;
        return;
    }
    int node = (i4 * 4) >> 7;
    int trn = flags[node];
    f32x4 m = __builtin_nontemporal_load(reinterpret_cast<const f32x4*>(M) + i4);
    f32x4 xv = __builtin_nontemporal_load(reinterpret_cast<const f32x4*>(x) + i4);
    float me0 = trn ? 1.0f : 1.0f / (1.0f + __expf(-m.x));
    float me1 = trn ? 1.0f : 1.0f / (1.0f + __expf(-m.y));
    float me2 = trn ? 1.0f : 1.0f / (1.0f + __expf(-m.z));
    float me3 = trn ? 1.0f : 1.0f / (1.0f + __expf(-m.w));
    u32x4 q;
    q.x = bf16_rne(me0) | (bf16_rne(me0 * xv.x) << 16);
    q.y = bf16_rne(me1) | (bf16_rne(me1 * xv.y) << 16);
    q.z = bf16_rne(me2) | (bf16_rne(me2 * xv.z) << 16);
    q.w = bf16_rne(me3) | (bf16_rne(me3 * xv.w) << 16);
    Q4[i4] = q;
}

// ---------- bucket fill: 4 edges/thread, padded counters ----------
__global__ __launch_bounds__(256)
void k_fillb(const int* __restrict__ rows, const int* __restrict__ cols,
             const float* __restrict__ adj, int* __restrict__ counts,
             unsigned* __restrict__ eca) {
    int i = blockIdx.x * blockDim.x + threadIdx.x;
    if (i >= NE / 4) return;
    i32x4 r = __builtin_nontemporal_load(reinterpret_cast<const i32x4*>(rows) + i);
    i32x4 c = __builtin_nontemporal_load(reinterpret_cast<const i32x4*>(cols) + i);
    f32x4 a = __builtin_nontemporal_load(reinterpret_cast<const f32x4*>(adj) + i);
    int p0 = atomicAdd(&counts[r.x * CSTR], 1);
    int p1 = atomicAdd(&counts[r.y * CSTR], 1);
    int p2 = atomicAdd(&counts[r.z * CSTR], 1);
    int p3 = atomicAdd(&counts[r.w * CSTR], 1);
    unsigned h0 = (unsigned)__half_as_ushort(__float2half_rn(a.x));
    unsigned h1 = (unsigned)__half_as_ushort(__float2half_rn(a.y));
    unsigned h2 = (unsigned)__half_as_ushort(__float2half_rn(a.z));
    unsigned h3 = (unsigned)__half_as_ushort(__float2half_rn(a.w));
    if (p0 < CAP)
        __builtin_nontemporal_store((unsigned)c.x | (h0 << 16), &eca[r.x * CAP + p0]);
    if (p1 < CAP)
        __builtin_nontemporal_store((unsigned)c.y | (h1 << 16), &eca[r.y * CAP + p1]);
    if (p2 < CAP)
        __builtin_nontemporal_store((unsigned)c.z | (h2 << 16), &eca[r.z * CAP + p2]);
    if (p3 < CAP)
        __builtin_nontemporal_store((unsigned)c.w | (h3 << 16), &eca[r.w * CAP + p3]);
}

// ---------- gather: one wave per 2 rows, branch-free padded loop ----------
__global__ __launch_bounds__(256)
void k_gather(const int* __restrict__ counts, const unsigned* __restrict__ eca,
              const unsigned* __restrict__ Q, unsigned* __restrict__ Hnb) {
    int t = blockIdx.x * blockDim.x + threadIdx.x;
    int wv = t >> 6;
    int lane = t & 63;
    int ra = wv * 2, rb = ra + 1;   // NN even -> rb < NN whenever ra < NN
    if (ra >= NN) return;
    int dega = min(counts[ra * CSTR], CAP);
    int degb = min(counts[rb * CSTR], CAP);
    int nmax = (max(dega, degb) + 3) >> 2;
    const u32x4* ebA = reinterpret_cast<const u32x4*>(eca + (size_t)ra * CAP);
    const u32x4* ebB = reinterpret_cast<const u32x4*>(eca + (size_t)rb * CAP);
    const u32x2* Q2 = reinterpret_cast<const u32x2*>(Q);
    float da0 = 0.f, da1 = 0.f, ha0 = 0.f, ha1 = 0.f;
    float db0 = 0.f, db1 = 0.f, hb0 = 0.f, hb1 = 0.f;
    for (int c = 0; c < nmax; ++c) {
        u32x4 eA = __builtin_nontemporal_load(ebA + c);  // pads contribute 0
        u32x4 eB = __builtin_nontemporal_load(ebB + c);
        unsigned ea[4] = {eA.x, eA.y, eA.z, eA.w};
        unsigned eb[4] = {eB.x, eB.y, eB.z, eB.w};
#pragma unroll
        for (int i = 0; i < 4; ++i) {
            unsigned ca = ea[i] & 0xFFFFu, cb = eb[i] & 0xFFFFu;
            float aa = __half2float(__ushort_as_half((unsigned short)(ea[i] >> 16)));
            float ab = __half2float(__ushort_as_half((unsigned short)(eb[i] >> 16)));
            u32x2 qa = Q2[(int)ca * 64 + lane];
            u32x2 qb = Q2[(int)cb * 64 + lane];
            da0 += __uint_as_float(qa.x << 16);
            da1 += __uint_as_float(qa.y << 16);
            ha0 += aa * __uint_as_float(qa.x & 0xFFFF0000u);
            ha1 += aa * __uint_as_float(qa.y & 0xFFFF0000u);
            db0 += __uint_as_float(qb.x << 16);
            db1 += __uint_as_float(qb.y << 16);
            hb0 += ab * __uint_as_float(qb.x & 0xFFFF0000u);
            hb1 += ab * __uint_as_float(qb.y & 0xFFFF0000u);
        }
    }
    float oa0 = (da0 == 0.f) ? 0.f : ha0 / da0;
    float oa1 = (da1 == 0.f) ? 0.f : ha1 / da1;
    float ob0 = (db0 == 0.f) ? 0.f : hb0 / db0;
    float ob1 = (db1 == 0.f) ? 0.f : hb1 / db1;
    Hnb[ra * 64 + lane] = bf16_rne(oa0) | (bf16_rne(oa1) << 16);
    Hnb[rb * 64 + lane] = bf16_rne(ob0) | (bf16_rne(ob1) << 16);
}

// ---------- out = elu(Hn @ W) via MFMA bf16 ----------
__global__ __launch_bounds__(256)
void k_gemm(const unsigned* __restrict__ Hnb, const float* __restrict__ W,
            float* __restrict__ out) {
    __shared__ short Wb[128 * 128];  // 32KB: [((t*4+ks)*64 + l)*8 + j]
    int tid = threadIdx.x;

#pragma unroll
    for (int i = 0; i < 8; ++i) {
        int c = tid + i * 256;            // 0..2047
        int nl = c & 15;
        int t8 = (c >> 4) & 7;
        int ks = (c >> 7) & 3;
        int lh = (c >> 9) & 3;
        int l = nl | (lh << 4);
        int n = t8 * 16 + nl;
        int k0 = ks * 32 + lh * 8;
        short v[8];
#pragma unroll
        for (int j = 0; j < 8; ++j)
            v[j] = (short)bf16_rne(W[(k0 + j) * 128 + n]);
        *reinterpret_cast<bf16x8*>(&Wb[((t8 * 4 + ks) * 64 + l) * 8]) =
            *reinterpret_cast<bf16x8*>(v);
    }
    __syncthreads();

    int wave = tid >> 6, lane = tid & 63;
    int r0 = blockIdx.x * 64 + wave * 16;
    int mrow = lane & 15;
    int kg = lane >> 4;
    int arow = min(r0 + mrow, NN - 1);
    const u32x4* H4 = reinterpret_cast<const u32x4*>(Hnb);

    bf16x8 a[4];
#pragma unroll
    for (int ks = 0; ks < 4; ++ks) {
        u32x4 v = H4[(size_t)arow * 16 + ks * 4 + kg];
        a[ks] = *reinterpret_cast<bf16x8*>(&v);
    }

    f32x4 acc[8];
#pragma unroll
    for (int t8 = 0; t8 < 8; ++t8) acc[t8] = (f32x4){0.f, 0.f, 0.f, 0.f};

#pragma unroll
    for (int t8 = 0; t8 < 8; ++t8) {
#pragma unroll
        for (int ks = 0; ks < 4; ++ks) {
            bf16x8 b = *reinterpret_cast<const bf16x8*>(
                &Wb[((t8 * 4 + ks) * 64 + lane) * 8]);
            acc[t8] = __builtin_amdgcn_mfma_f32_16x16x32_bf16(a[ks], b, acc[t8], 0, 0, 0);
        }
    }

    // C/D layout: col = lane&15, row = (lane>>4)*4 + reg  [m89-verified]
    int colb = lane & 15;
    int rsub = (lane >> 4) * 4;
#pragma unroll
    for (int t8 = 0; t8 < 8; ++t8) {
#pragma unroll
        for (int rg = 0; rg < 4; ++rg) {
            int row = r0 + rsub + rg;
            if (row < NN) {
                float v = acc[t8][rg];
                float o = (v > 0.f) ? v : (__expf(v) - 1.0f);
                __builtin_nontemporal_store(o, &out[(size_t)row * 128 + t8 * 16 + colb]);
            }
        }
    }
}

// ================= fallback (atomic scatter) if ws is small =================
__global__ void k_init_fb(float* __restrict__ denomH, int* __restrict__ flags) {
    int i = blockIdx.x * blockDim.x + threadIdx.x;
    const int total4 = (2 * NF) / 4;
    if (i < total4)
        reinterpret_cast<float4*>(denomH)[i] = make_float4(0.f, 0.f, 0.f, 0.f);
    if (i < NN) flags[i] = 0;
}

__global__ __launch_bounds__(256)
void k_edge_fb(const int* __restrict__ rows, const int* __restrict__ cols,
               const float* __restrict__ adj, const float* __restrict__ M,
               const int* __restrict__ flags, const float* __restrict__ x,
               float* __restrict__ denom, float* __restrict__ H) {
    int t = blockIdx.x * blockDim.x + threadIdx.x;
    int e = t >> 6;
    int lane = t & 63;
    if (e >= NE) return;
    int r = rows[e], c = cols[e];
    float a = adj[e];
#pragma unroll
    for (int i = 0; i < 2; ++i) {
        int f = lane + i * 64;
        float m = M[c * FF + f];
        float me = flags[c] ? 1.0f : 1.0f / (1.0f + __expf(-m));
        float xv = x[c * FF + f];
        unsafeAtomicAdd(&denom[r * FF + f], me);
        unsafeAtomicAdd(&H[r * FF + f], a * me * xv);
    }
}

__global__ __launch_bounds__(256)
void k_norm_fb(const float* __restrict__ H, const float* __restrict__ denom,
               float* __restrict__ Hn) {
    int i = blockIdx.x * blockDim.x + threadIdx.x;
    if (i >= NF) return;
    float d = denom[i];
    Hn[i] = (d == 0.f) ? 0.f : H[i] / d;
}

__global__ __launch_bounds__(256)
void k_gemm_fb(const float* __restrict__ Hn, const float* __restrict__ W,
               float* __restrict__ out) {
    __shared__ float Ws[128][128];
    __shared__ float Hs[32][128];
    int tid = threadIdx.x;
    const float4* W4 = reinterpret_cast<const float4*>(W);
    float4* Ws4 = reinterpret_cast<float4*>(&Ws[0][0]);
#pragma unroll
    for (int i = 0; i < 16; ++i) Ws4[tid + i * 256] = W4[tid + i * 256];
    int r0 = blockIdx.x * 32;
    const float4* H4 = reinterpret_cast<const float4*>(Hn);
    float4* Hs4 = reinterpret_cast<float4*>(&Hs[0][0]);
#pragma unroll
    for (int i = 0; i < 4; ++i) {
        int m = tid + i * 256;
        int r = m >> 5, k4 = m & 31;
        int row = r0 + r;
        Hs4[m] = (row < NN) ? H4[row * 32 + k4] : make_float4(0.f, 0.f, 0.f, 0.f);
    }
    __syncthreads();
    int c = tid & 127, rg = tid >> 7;
    float acc[16];
#pragma unroll
    for (int i = 0; i < 16; ++i) acc[i] = 0.f;
    for (int k = 0; k < 128; k += 4) {
        float w0 = Ws[k][c], w1 = Ws[k + 1][c], w2 = Ws[k + 2][c], w3 = Ws[k + 3][c];
#pragma unroll
        for (int i = 0; i < 16; ++i) {
            float4 h = *reinterpret_cast<const float4*>(&Hs[rg * 16 + i][k]);
            acc[i] += h.x * w0 + h.y * w1 + h.z * w2 + h.w * w3;
        }
    }
#pragma unroll
    for (int i = 0; i < 16; ++i) {
        int row = r0 + rg * 16 + i;
        if (row < NN) {
            float v = acc[i];
            out[row * 128 + c] = (v > 0.f) ? v : (__expf(v) - 1.0f);
        }
    }
}

extern "C" void kernel_launch(void* const* d_in, const int* in_sizes, int n_in,
                              void* d_out, int out_size, void* d_ws, size_t ws_size,
                              hipStream_t stream) {
    const float* x     = (const float*)d_in[0];
    const int*   erows = (const int*)d_in[1];
    const int*   ecols = (const int*)d_in[2];
    const float* adj   = (const float*)d_in[3];
    const int*   train = (const int*)d_in[4];
    const float* M     = (const float*)d_in[5];
    const float* W     = (const float*)d_in[6];
    float* out = (float*)d_out;
    float* ws  = (float*)d_ws;

    // ws layout (4-byte units):
    // [Q: NF+FF][Hnb: NF/2][eca: NN*CAP][counts: NN*CSTR][flags: NN]
    size_t fo = 0;
    unsigned* Q   = (unsigned*)(ws + fo); fo += NF + FF;
    unsigned* Hnb = (unsigned*)(ws + fo); fo += NF / 2;
    unsigned* eca = (unsigned*)(ws + fo); fo += (size_t)NN * CAP;
    int* counts   = (int*)(ws + fo); fo += (size_t)NN * CSTR;
    int* flags    = (int*)(ws + fo); fo += NN;
    const size_t need = fo * 4;  // ~54.6 MB

    if (ws_size >= need) {
        k_zero<<<((NN * CAP / 4) + 255) / 256, 256, 0, stream>>>(counts, flags, eca);
        k_flags<<<(NT + 255) / 256, 256, 0, stream>>>(train, flags);
        k_pack<<<(NF / 4 + FF / 4 + 255) / 256, 256, 0, stream>>>(M, x, flags, Q);
        k_fillb<<<(NE / 4 + 255) / 256, 256, 0, stream>>>(erows, ecols, adj, counts, eca);
        k_gather<<<((NN / 2) * 64 + 255) / 256, 256, 0, stream>>>(counts, eca, Q, Hnb);
        k_gemm<<<(NN + 63) / 64, 256, 0, stream>>>(Hnb, W, out);
    } else {
        float* denom = ws;
        float* H     = ws + NF;
        int* flags_fb = (int*)(ws + 2 * (size_t)NF);
        k_init_fb<<<(2 * NF / 4 + 255) / 256, 256, 0, stream>>>(denom, flags_fb);
        k_flags<<<(NT + 255) / 256, 256, 0, stream>>>(train, flags_fb);
        k_edge_fb<<<((size_t)NE * 64 + 255) / 256, 256, 0, stream>>>(
            erows, ecols, adj, M, flags_fb, x, denom, H);
        k_norm_fb<<<(NF + 255) / 256, 256, 0, stream>>>(H, denom, denom);
        k_gemm_fb<<<(NN + 31) / 32, 256, 0, stream>>>(denom, W, out);
    }
}

// Round 9
// 115.642 us; speedup vs baseline: 1.4183x; 1.3346x over previous
//
#include <hip/hip_runtime.h>
#include <hip/hip_fp16.h>

#define NN 50000      // nodes
#define FF 128        // features
#define NE 800000     // edges
#define NT 5000       // train ids
#define NF (NN * FF)  // 6,400,000
#define NBKT 196      // coarse buckets: row>>8 in [0,196)
#define BCAP 8192     // bucket capacity (avg 4082, sigma ~64 -> 64 sigma margin)
#define PADCOL 50000u // zero Q row

typedef __attribute__((ext_vector_type(8))) short bf16x8;
typedef __attribute__((ext_vector_type(4))) float f32x4;
typedef __attribute__((ext_vector_type(4))) unsigned u32x4;
typedef __attribute__((ext_vector_type(2))) unsigned u32x2;
typedef __attribute__((ext_vector_type(4))) int i32x4;

__device__ __forceinline__ unsigned bf16_rne(float f) {
    unsigned u = __float_as_uint(f);
    return (u + 0x7FFFu + ((u >> 16) & 1u)) >> 16;
}

// ---------- init: zero bucket cursors + flags ----------
__global__ void k_init(int* __restrict__ gcur, int* __restrict__ flags) {
    int i = blockIdx.x * blockDim.x + threadIdx.x;
    if (i < 256) gcur[i] = 0;
    if (i < NN) flags[i] = 0;
}

__global__ void k_flags(const int* __restrict__ ids, int* __restrict__ flags) {
    int i = blockIdx.x * blockDim.x + threadIdx.x;
    if (i < NT) flags[ids[i]] = 1;
}

// ---------- pack Q[n][f] = (bf16(me) | bf16(me*x)<<16); row NN = 0 ----------
__global__ void k_pack(const float* __restrict__ M, const float* __restrict__ x,
                       const int* __restrict__ flags, unsigned* __restrict__ Q) {
    int i4 = blockIdx.x * blockDim.x + threadIdx.x;  // one float4 (4 features)
    if (i4 >= NF / 4 + FF / 4) return;
    u32x4* Q4 = reinterpret_cast<u32x4*>(Q);
    if (i4 >= NF / 4) {  // zero pad row (node NN)
        u32x4 z = {0, 0, 0, 0};
        Q4[i4] = z;
        return;
    }
    int node = (i4 * 4) >> 7;
    int trn = flags[node];
    f32x4 m = __builtin_nontemporal_load(reinterpret_cast<const f32x4*>(M) + i4);
    f32x4 xv = __builtin_nontemporal_load(reinterpret_cast<const f32x4*>(x) + i4);
    float me0 = trn ? 1.0f : 1.0f / (1.0f + __expf(-m.x));
    float me1 = trn ? 1.0f : 1.0f / (1.0f + __expf(-m.y));
    float me2 = trn ? 1.0f : 1.0f / (1.0f + __expf(-m.z));
    float me3 = trn ? 1.0f : 1.0f / (1.0f + __expf(-m.w));
    u32x4 q;
    q.x = bf16_rne(me0) | (bf16_rne(me0 * xv.x) << 16);
    q.y = bf16_rne(me1) | (bf16_rne(me1 * xv.y) << 16);
    q.z = bf16_rne(me2) | (bf16_rne(me2 * xv.z) << 16);
    q.w = bf16_rne(me3) | (bf16_rne(me3 * xv.w) << 16);
    Q4[i4] = q;
}

// ---------- pass1: coarse bucket scatter (8B records, chunked coalesced) ----
__global__ __launch_bounds__(1024)
void k_pass1(const int* __restrict__ rows, const int* __restrict__ cols,
             const float* __restrict__ adj, int* __restrict__ gcur,
             unsigned long long* __restrict__ ebuf) {
    __shared__ int hist[256];
    __shared__ int cur[256];
    int t = threadIdx.x;
    if (t < 256) hist[t] = 0;
    __syncthreads();
    int base = blockIdx.x * 8192;
    int r[8], c[8], bkt[8];
    float a[8];
#pragma unroll
    for (int k = 0; k < 8; ++k) {
        int idx = base + k * 1024 + t;
        bool v = idx < NE;
        r[k] = v ? rows[idx] : 0;
        c[k] = v ? cols[idx] : 0;
        a[k] = v ? adj[idx] : 0.f;
        bkt[k] = v ? (r[k] >> 8) : -1;
        if (v) atomicAdd(&hist[bkt[k]], 1);
    }
    __syncthreads();
    if (t < 256) {
        int cnt = hist[t];
        int b = 0;
        if (cnt > 0) b = atomicAdd(&gcur[t], cnt);
        cur[t] = b;
    }
    __syncthreads();
#pragma unroll
    for (int k = 0; k < 8; ++k) {
        if (bkt[k] >= 0) {
            int p = atomicAdd(&cur[bkt[k]], 1);
            if (p < BCAP) {
                unsigned h = (unsigned)__half_as_ushort(__float2half_rn(a[k]));
                unsigned pk = (unsigned)c[k] | (h << 16);
                ebuf[(size_t)bkt[k] * BCAP + p] =
                    ((unsigned long long)(r[k] & 255) << 32) | pk;
            }
        }
    }
}

// ---------- scan of bucket counts -> bucket bases ----------
__global__ void k_scanb(const int* __restrict__ gcur, int* __restrict__ gbase) {
    __shared__ int part[256];
    int t = threadIdx.x;
    int own = min(gcur[t], BCAP);
    part[t] = own;
    __syncthreads();
    for (int d = 1; d < 256; d <<= 1) {
        int v = (t >= d) ? part[t - d] : 0;
        __syncthreads();
        part[t] += v;
        __syncthreads();
    }
    gbase[t] = part[t] - own;
}

// ---------- pass2: per-bucket fine CSR (LDS hist+scan, coalesced out) ------
__global__ __launch_bounds__(1024)
void k_pass2(const int* __restrict__ gcur, const int* __restrict__ gbase,
             const unsigned long long* __restrict__ ebuf,
             unsigned* __restrict__ gedges, int* __restrict__ offsets) {
    __shared__ int hist[256];
    __shared__ int scan[256];
    __shared__ int cur[256];
    int b = blockIdx.x;
    int t = threadIdx.x;
    int cnt = min(gcur[b], BCAP);
    int gstart = gbase[b];
    if (t < 256) hist[t] = 0;
    __syncthreads();
    const unsigned long long* eb = ebuf + (size_t)b * BCAP;
    unsigned long long rec[8];
    int nk = (cnt + 1023) >> 10;
    for (int k = 0; k < nk; ++k) {
        int idx = k * 1024 + t;
        rec[k] = 0;
        if (idx < cnt) {
            rec[k] = eb[idx];
            atomicAdd(&hist[(int)(rec[k] >> 32)], 1);
        }
    }
    __syncthreads();
    if (t < 256) scan[t] = hist[t];
    __syncthreads();
    for (int d = 1; d < 256; d <<= 1) {
        int v = (t < 256 && t >= d) ? scan[t - d] : 0;
        __syncthreads();
        if (t < 256) scan[t] += v;
        __syncthreads();
    }
    if (t < 256) {
        int excl = scan[t] - hist[t];
        cur[t] = excl;
        int row = b * 256 + t;
        if (row < NN) offsets[row] = gstart + excl;
    }
    if (b == NBKT - 1 && t == 0) offsets[NN] = gstart + cnt;
    __syncthreads();
    for (int k = 0; k < nk; ++k) {
        int idx = k * 1024 + t;
        if (idx < cnt) {
            int lr = (int)(rec[k] >> 32);
            int p = atomicAdd(&cur[lr], 1);
            gedges[gstart + p] = (unsigned)(rec[k] & 0xFFFFFFFFu);
        }
    }
}

// ---------- gather: one wave per 2 rows, CSR, tail-predicated ----------
__global__ __launch_bounds__(256)
void k_gather(const int* __restrict__ offsets, const unsigned* __restrict__ gedges,
              const unsigned* __restrict__ Q, unsigned* __restrict__ Hnb) {
    int t = blockIdx.x * blockDim.x + threadIdx.x;
    int wv = t >> 6;
    int lane = t & 63;
    int ra = wv * 2, rb = ra + 1;   // NN even
    if (ra >= NN) return;
    int ba = offsets[ra];
    int bb = offsets[rb];           // == end of ra
    int eb2 = offsets[rb + 1];
    int dega = bb - ba, degb = eb2 - bb;
    int nmax = (max(dega, degb) + 3) >> 2;
    const u32x2* Q2 = reinterpret_cast<const u32x2*>(Q);
    const unsigned padrec = PADCOL;  // col=50000 (zero row), adj=0
    float da0 = 0.f, da1 = 0.f, ha0 = 0.f, ha1 = 0.f;
    float db0 = 0.f, db1 = 0.f, hb0 = 0.f, hb1 = 0.f;
    for (int c = 0; c < nmax; ++c) {
        int ia = ba + c * 4, ib = bb + c * 4;
        unsigned ea[4], ebv[4];
#pragma unroll
        for (int i = 0; i < 4; ++i) {
            ea[i]  = (ia + i < bb)  ? gedges[ia + i] : padrec;
            ebv[i] = (ib + i < eb2) ? gedges[ib + i] : padrec;
        }
#pragma unroll
        for (int i = 0; i < 4; ++i) {
            unsigned ca = ea[i] & 0xFFFFu, cb = ebv[i] & 0xFFFFu;
            float aa = __half2float(__ushort_as_half((unsigned short)(ea[i] >> 16)));
            float ab = __half2float(__ushort_as_half((unsigned short)(ebv[i] >> 16)));
            u32x2 qa = Q2[(int)ca * 64 + lane];
            u32x2 qb = Q2[(int)cb * 64 + lane];
            da0 += __uint_as_float(qa.x << 16);
            da1 += __uint_as_float(qa.y << 16);
            ha0 += aa * __uint_as_float(qa.x & 0xFFFF0000u);
            ha1 += aa * __uint_as_float(qa.y & 0xFFFF0000u);
            db0 += __uint_as_float(qb.x << 16);
            db1 += __uint_as_float(qb.y << 16);
            hb0 += ab * __uint_as_float(qb.x & 0xFFFF0000u);
            hb1 += ab * __uint_as_float(qb.y & 0xFFFF0000u);
        }
    }
    float oa0 = (da0 == 0.f) ? 0.f : ha0 / da0;
    float oa1 = (da1 == 0.f) ? 0.f : ha1 / da1;
    float ob0 = (db0 == 0.f) ? 0.f : hb0 / db0;
    float ob1 = (db1 == 0.f) ? 0.f : hb1 / db1;
    Hnb[ra * 64 + lane] = bf16_rne(oa0) | (bf16_rne(oa1) << 16);
    Hnb[rb * 64 + lane] = bf16_rne(ob0) | (bf16_rne(ob1) << 16);
}

// ---------- out = elu(Hn @ W) via MFMA bf16 ----------
__global__ __launch_bounds__(256)
void k_gemm(const unsigned* __restrict__ Hnb, const float* __restrict__ W,
            float* __restrict__ out) {
    __shared__ short Wb[128 * 128];  // 32KB: [((t*4+ks)*64 + l)*8 + j]
    int tid = threadIdx.x;

#pragma unroll
    for (int i = 0; i < 8; ++i) {
        int c = tid + i * 256;            // 0..2047
        int nl = c & 15;
        int t8 = (c >> 4) & 7;
        int ks = (c >> 7) & 3;
        int lh = (c >> 9) & 3;
        int l = nl | (lh << 4);
        int n = t8 * 16 + nl;
        int k0 = ks * 32 + lh * 8;
        short v[8];
#pragma unroll
        for (int j = 0; j < 8; ++j)
            v[j] = (short)bf16_rne(W[(k0 + j) * 128 + n]);
        *reinterpret_cast<bf16x8*>(&Wb[((t8 * 4 + ks) * 64 + l) * 8]) =
            *reinterpret_cast<bf16x8*>(v);
    }
    __syncthreads();

    int wave = tid >> 6, lane = tid & 63;
    int r0 = blockIdx.x * 64 + wave * 16;
    int mrow = lane & 15;
    int kg = lane >> 4;
    int arow = min(r0 + mrow, NN - 1);
    const u32x4* H4 = reinterpret_cast<const u32x4*>(Hnb);

    bf16x8 a[4];
#pragma unroll
    for (int ks = 0; ks < 4; ++ks) {
        u32x4 v = H4[(size_t)arow * 16 + ks * 4 + kg];
        a[ks] = *reinterpret_cast<bf16x8*>(&v);
    }

    f32x4 acc[8];
#pragma unroll
    for (int t8 = 0; t8 < 8; ++t8) acc[t8] = (f32x4){0.f, 0.f, 0.f, 0.f};

#pragma unroll
    for (int t8 = 0; t8 < 8; ++t8) {
#pragma unroll
        for (int ks = 0; ks < 4; ++ks) {
            bf16x8 b = *reinterpret_cast<const bf16x8*>(
                &Wb[((t8 * 4 + ks) * 64 + lane) * 8]);
            acc[t8] = __builtin_amdgcn_mfma_f32_16x16x32_bf16(a[ks], b, acc[t8], 0, 0, 0);
        }
    }

    // C/D layout: col = lane&15, row = (lane>>4)*4 + reg  [m89-verified]
    int colb = lane & 15;
    int rsub = (lane >> 4) * 4;
#pragma unroll
    for (int t8 = 0; t8 < 8; ++t8) {
#pragma unroll
        for (int rg = 0; rg < 4; ++rg) {
            int row = r0 + rsub + rg;
            if (row < NN) {
                float v = acc[t8][rg];
                float o = (v > 0.f) ? v : (__expf(v) - 1.0f);
                __builtin_nontemporal_store(o, &out[(size_t)row * 128 + t8 * 16 + colb]);
            }
        }
    }
}

// ================= fallback (atomic scatter) if ws is small =================
__global__ void k_init_fb(float* __restrict__ denomH, int* __restrict__ flags) {
    int i = blockIdx.x * blockDim.x + threadIdx.x;
    const int total4 = (2 * NF) / 4;
    if (i < total4)
        reinterpret_cast<float4*>(denomH)[i] = make_float4(0.f, 0.f, 0.f, 0.f);
    if (i < NN) flags[i] = 0;
}

__global__ __launch_bounds__(256)
void k_edge_fb(const int* __restrict__ rows, const int* __restrict__ cols,
               const float* __restrict__ adj, const float* __restrict__ M,
               const int* __restrict__ flags, const float* __restrict__ x,
               float* __restrict__ denom, float* __restrict__ H) {
    int t = blockIdx.x * blockDim.x + threadIdx.x;
    int e = t >> 6;
    int lane = t & 63;
    if (e >= NE) return;
    int r = rows[e], c = cols[e];
    float a = adj[e];
#pragma unroll
    for (int i = 0; i < 2; ++i) {
        int f = lane + i * 64;
        float m = M[c * FF + f];
        float me = flags[c] ? 1.0f : 1.0f / (1.0f + __expf(-m));
        float xv = x[c * FF + f];
        unsafeAtomicAdd(&denom[r * FF + f], me);
        unsafeAtomicAdd(&H[r * FF + f], a * me * xv);
    }
}

__global__ __launch_bounds__(256)
void k_norm_fb(const float* __restrict__ H, const float* __restrict__ denom,
               float* __restrict__ Hn) {
    int i = blockIdx.x * blockDim.x + threadIdx.x;
    if (i >= NF) return;
    float d = denom[i];
    Hn[i] = (d == 0.f) ? 0.f : H[i] / d;
}

__global__ __launch_bounds__(256)
void k_gemm_fb(const float* __restrict__ Hn, const float* __restrict__ W,
               float* __restrict__ out) {
    __shared__ float Ws[128][128];
    __shared__ float Hs[32][128];
    int tid = threadIdx.x;
    const float4* W4 = reinterpret_cast<const float4*>(W);
    float4* Ws4 = reinterpret_cast<float4*>(&Ws[0][0]);
#pragma unroll
    for (int i = 0; i < 16; ++i) Ws4[tid + i * 256] = W4[tid + i * 256];
    int r0 = blockIdx.x * 32;
    const float4* H4 = reinterpret_cast<const float4*>(Hn);
    float4* Hs4 = reinterpret_cast<float4*>(&Hs[0][0]);
#pragma unroll
    for (int i = 0; i < 4; ++i) {
        int m = tid + i * 256;
        int r = m >> 5, k4 = m & 31;
        int row = r0 + r;
        Hs4[m] = (row < NN) ? H4[row * 32 + k4] : make_float4(0.f, 0.f, 0.f, 0.f);
    }
    __syncthreads();
    int c = tid & 127, rg = tid >> 7;
    float acc[16];
#pragma unroll
    for (int i = 0; i < 16; ++i) acc[i] = 0.f;
    for (int k = 0; k < 128; k += 4) {
        float w0 = Ws[k][c], w1 = Ws[k + 1][c], w2 = Ws[k + 2][c], w3 = Ws[k + 3][c];
#pragma unroll
        for (int i = 0; i < 16; ++i) {
            float4 h = *reinterpret_cast<const float4*>(&Hs[rg * 16 + i][k]);
            acc[i] += h.x * w0 + h.y * w1 + h.z * w2 + h.w * w3;
        }
    }
#pragma unroll
    for (int i = 0; i < 16; ++i) {
        int row = r0 + rg * 16 + i;
        if (row < NN) {
            float v = acc[i];
            out[row * 128 + c] = (v > 0.f) ? v : (__expf(v) - 1.0f);
        }
    }
}

extern "C" void kernel_launch(void* const* d_in, const int* in_sizes, int n_in,
                              void* d_out, int out_size, void* d_ws, size_t ws_size,
                              hipStream_t stream) {
    const float* x     = (const float*)d_in[0];
    const int*   erows = (const int*)d_in[1];
    const int*   ecols = (const int*)d_in[2];
    const float* adj   = (const float*)d_in[3];
    const int*   train = (const int*)d_in[4];
    const float* M     = (const float*)d_in[5];
    const float* W     = (const float*)d_in[6];
    float* out = (float*)d_out;
    float* ws  = (float*)d_ws;

    // ws layout (4-byte units):
    // [Q: NF+FF][union: Hnb (NF/2) / ebuf (NBKT*BCAP*2)][gedges: NE]
    // [offsets: NN+1][gcur: 256][gbase: 256][flags: NN]
    const size_t UNI = ((size_t)NBKT * BCAP * 2 > (size_t)NF / 2)
                           ? (size_t)NBKT * BCAP * 2 : (size_t)NF / 2;
    size_t fo = 0;
    unsigned* Q   = (unsigned*)(ws + fo); fo += NF + FF;
    unsigned* Hnb = (unsigned*)(ws + fo);
    unsigned long long* ebuf = (unsigned long long*)(ws + fo); fo += UNI;
    unsigned* gedges = (unsigned*)(ws + fo); fo += NE;
    int* offsets  = (int*)(ws + fo); fo += NN + 1;
    int* gcur     = (int*)(ws + fo); fo += 256;
    int* gbase    = (int*)(ws + fo); fo += 256;
    int* flags    = (int*)(ws + fo); fo += NN;
    const size_t need = fo * 4;  // ~42 MB

    if (ws_size >= need) {
        k_init<<<(NN + 255) / 256, 256, 0, stream>>>(gcur, flags);
        k_flags<<<(NT + 255) / 256, 256, 0, stream>>>(train, flags);
        k_pack<<<(NF / 4 + FF / 4 + 255) / 256, 256, 0, stream>>>(M, x, flags, Q);
        k_pass1<<<(NE + 8191) / 8192, 1024, 0, stream>>>(erows, ecols, adj, gcur, ebuf);
        k_scanb<<<1, 256, 0, stream>>>(gcur, gbase);
        k_pass2<<<NBKT, 1024, 0, stream>>>(gcur, gbase, ebuf, gedges, offsets);
        k_gather<<<((NN / 2) * 64 + 255) / 256, 256, 0, stream>>>(offsets, gedges, Q, Hnb);
        k_gemm<<<(NN + 63) / 64, 256, 0, stream>>>(Hnb, W, out);
    } else {
        float* denom = ws;
        float* H     = ws + NF;
        int* flags_fb = (int*)(ws + 2 * (size_t)NF);
        k_init_fb<<<(2 * NF / 4 + 255) / 256, 256, 0, stream>>>(denom, flags_fb);
        k_flags<<<(NT + 255) / 256, 256, 0, stream>>>(train, flags_fb);
        k_edge_fb<<<((size_t)NE * 64 + 255) / 256, 256, 0, stream>>>(
            erows, ecols, adj, M, flags_fb, x, denom, H);
        k_norm_fb<<<(NF + 255) / 256, 256, 0, stream>>>(H, denom, denom);
        k_gemm_fb<<<(NN + 31) / 32, 256, 0, stream>>>(denom, W, out);
    }
}

// Round 10
// 107.279 us; speedup vs baseline: 1.5289x; 1.0780x over previous
//
#include <hip/hip_runtime.h>
#include <hip/hip_fp16.h>

#define NN 50000      // nodes
#define FF 128        // features
#define NE 800000     // edges
#define NT 5000       // train ids
#define NF (NN * FF)  // 6,400,000
#define NBKT 196      // coarse buckets: row>>8 in [0,196)
#define BCAP 8192     // bucket capacity (avg 4082)
#define PADCOL 50000u // zero Q row
#define P1BLK 98      // pass1 blocks
#define TRN_THREADS (NT * 32)  // train overwrite: one thread per (id, feat4)

typedef __attribute__((ext_vector_type(8))) short bf16x8;
typedef __attribute__((ext_vector_type(4))) float f32x4;
typedef __attribute__((ext_vector_type(4))) unsigned u32x4;
typedef __attribute__((ext_vector_type(2))) unsigned u32x2;
typedef __attribute__((ext_vector_type(4))) int i32x4;

__device__ __forceinline__ unsigned bf16_rne(float f) {
    unsigned u = __float_as_uint(f);
    return (u + 0x7FFFu + ((u >> 16) & 1u)) >> 16;
}

// ---------- pack Q[n][f] = (bf16(sigmoid) | bf16(sig*x)<<16); +gcur zero ----
__global__ void k_pack(const float* __restrict__ M, const float* __restrict__ x,
                       unsigned* __restrict__ Q, int* __restrict__ gcur) {
    int i4 = blockIdx.x * blockDim.x + threadIdx.x;
    if (i4 < 256) gcur[i4] = 0;
    if (i4 >= NF / 4 + FF / 4) return;
    u32x4* Q4 = reinterpret_cast<u32x4*>(Q);
    if (i4 >= NF / 4) {  // zero pad row (node NN)
        u32x4 z = {0, 0, 0, 0};
        Q4[i4] = z;
        return;
    }
    f32x4 m = __builtin_nontemporal_load(reinterpret_cast<const f32x4*>(M) + i4);
    f32x4 xv = __builtin_nontemporal_load(reinterpret_cast<const f32x4*>(x) + i4);
    float me0 = 1.0f / (1.0f + __expf(-m.x));
    float me1 = 1.0f / (1.0f + __expf(-m.y));
    float me2 = 1.0f / (1.0f + __expf(-m.z));
    float me3 = 1.0f / (1.0f + __expf(-m.w));
    u32x4 q;
    q.x = bf16_rne(me0) | (bf16_rne(me0 * xv.x) << 16);
    q.y = bf16_rne(me1) | (bf16_rne(me1 * xv.y) << 16);
    q.z = bf16_rne(me2) | (bf16_rne(me2 * xv.z) << 16);
    q.w = bf16_rne(me3) | (bf16_rne(me3 * xv.w) << 16);
    Q4[i4] = q;
}

// ---------- pass1 (blocks 0..97): coarse bucket scatter ----------
// blocks 98..: train-row overwrite (me=1, g=bf16(x)) -- runs after pack.
__global__ __launch_bounds__(1024)
void k_pass1(const int* __restrict__ rows, const int* __restrict__ cols,
             const float* __restrict__ adj, const int* __restrict__ train,
             const float* __restrict__ x, unsigned* __restrict__ Q,
             int* __restrict__ gcur, unsigned long long* __restrict__ ebuf) {
    int t = threadIdx.x;
    if (blockIdx.x >= P1BLK) {
        // ---- train overwrite part ----
        int g = (blockIdx.x - P1BLK) * 1024 + t;
        if (g < TRN_THREADS) {
            int ti = g >> 5;       // train index
            int f4 = g & 31;       // which float4 of the row
            int id = train[ti];
            f32x4 xv = reinterpret_cast<const f32x4*>(x)[id * 32 + f4];
            u32x4 q;
            q.x = 0x3F80u | (bf16_rne(xv.x) << 16);
            q.y = 0x3F80u | (bf16_rne(xv.y) << 16);
            q.z = 0x3F80u | (bf16_rne(xv.z) << 16);
            q.w = 0x3F80u | (bf16_rne(xv.w) << 16);
            reinterpret_cast<u32x4*>(Q)[id * 32 + f4] = q;
        }
        return;
    }
    __shared__ int hist[256];
    __shared__ int cur[256];
    if (t < 256) hist[t] = 0;
    __syncthreads();
    int base = blockIdx.x * 8192;
    int r[8], c[8], bkt[8];
    float a[8];
#pragma unroll
    for (int k = 0; k < 8; ++k) {
        int idx = base + k * 1024 + t;
        bool v = idx < NE;
        r[k] = v ? rows[idx] : 0;
        c[k] = v ? cols[idx] : 0;
        a[k] = v ? adj[idx] : 0.f;
        bkt[k] = v ? (r[k] >> 8) : -1;
        if (v) atomicAdd(&hist[bkt[k]], 1);
    }
    __syncthreads();
    if (t < 256) {
        int cnt = hist[t];
        int b = 0;
        if (cnt > 0) b = atomicAdd(&gcur[t], cnt);
        cur[t] = b;
    }
    __syncthreads();
#pragma unroll
    for (int k = 0; k < 8; ++k) {
        if (bkt[k] >= 0) {
            int p = atomicAdd(&cur[bkt[k]], 1);
            if (p < BCAP) {
                unsigned h = (unsigned)__half_as_ushort(__float2half_rn(a[k]));
                unsigned pk = (unsigned)c[k] | (h << 16);
                ebuf[(size_t)bkt[k] * BCAP + p] =
                    ((unsigned long long)(r[k] & 255) << 32) | pk;
            }
        }
    }
}

// ---------- pass2: per-bucket fine CSR; inline bucket-base scan ----------
__global__ __launch_bounds__(1024)
void k_pass2(const int* __restrict__ gcur,
             const unsigned long long* __restrict__ ebuf,
             unsigned* __restrict__ gedges, int* __restrict__ offsets) {
    __shared__ int hist[256];
    __shared__ int scan[256];
    __shared__ int cur[256];
    __shared__ int bscan[256];
    int b = blockIdx.x;
    int t = threadIdx.x;
    // inline prefix over bucket counts
    if (t < 256) {
        bscan[t] = (t < NBKT) ? min(gcur[t], BCAP) : 0;
        hist[t] = 0;
    }
    __syncthreads();
    for (int d = 1; d < 256; d <<= 1) {
        int v = (t < 256 && t >= d) ? bscan[t - d] : 0;
        __syncthreads();
        if (t < 256) bscan[t] += v;
        __syncthreads();
    }
    int cnt = min(gcur[b], BCAP);
    int gstart = (b > 0) ? bscan[b - 1] : 0;
    const unsigned long long* eb = ebuf + (size_t)b * BCAP;
    unsigned long long rec[8];
#pragma unroll
    for (int k = 0; k < 8; ++k) {
        int idx = k * 1024 + t;
        rec[k] = 0;
        bool v = idx < cnt;
        if (v) {
            rec[k] = eb[idx];
            atomicAdd(&hist[(int)(rec[k] >> 32)], 1);
        }
    }
    __syncthreads();
    if (t < 256) scan[t] = hist[t];
    __syncthreads();
    for (int d = 1; d < 256; d <<= 1) {
        int v = (t < 256 && t >= d) ? scan[t - d] : 0;
        __syncthreads();
        if (t < 256) scan[t] += v;
        __syncthreads();
    }
    if (t < 256) {
        int excl = scan[t] - hist[t];
        cur[t] = excl;
        int row = b * 256 + t;
        if (row < NN) offsets[row] = gstart + excl;
    }
    if (b == NBKT - 1 && t == 0) offsets[NN] = gstart + cnt;
    __syncthreads();
#pragma unroll
    for (int k = 0; k < 8; ++k) {
        int idx = k * 1024 + t;
        if (idx < cnt) {
            int lr = (int)(rec[k] >> 32);
            int p = atomicAdd(&cur[lr], 1);
            gedges[gstart + p] = (unsigned)(rec[k] & 0xFFFFFFFFu);
        }
    }
}

// ---------- gather: one wave per 2 rows, CSR, tail-predicated ----------
__global__ __launch_bounds__(256)
void k_gather(const int* __restrict__ offsets, const unsigned* __restrict__ gedges,
              const unsigned* __restrict__ Q, unsigned* __restrict__ Hnb) {
    int t = blockIdx.x * blockDim.x + threadIdx.x;
    int wv = t >> 6;
    int lane = t & 63;
    int ra = wv * 2, rb = ra + 1;   // NN even
    if (ra >= NN) return;
    int ba = offsets[ra];
    int bb = offsets[rb];           // == end of ra
    int eb2 = offsets[rb + 1];
    int dega = bb - ba, degb = eb2 - bb;
    int nmax = (max(dega, degb) + 3) >> 2;
    const u32x2* Q2 = reinterpret_cast<const u32x2*>(Q);
    const unsigned padrec = PADCOL;  // col=50000 (zero row), adj=0
    float da0 = 0.f, da1 = 0.f, ha0 = 0.f, ha1 = 0.f;
    float db0 = 0.f, db1 = 0.f, hb0 = 0.f, hb1 = 0.f;
    for (int c = 0; c < nmax; ++c) {
        int ia = ba + c * 4, ib = bb + c * 4;
        unsigned ea[4], ebv[4];
#pragma unroll
        for (int i = 0; i < 4; ++i) {
            ea[i]  = (ia + i < bb)  ? gedges[ia + i] : padrec;
            ebv[i] = (ib + i < eb2) ? gedges[ib + i] : padrec;
        }
#pragma unroll
        for (int i = 0; i < 4; ++i) {
            unsigned ca = ea[i] & 0xFFFFu, cb = ebv[i] & 0xFFFFu;
            float aa = __half2float(__ushort_as_half((unsigned short)(ea[i] >> 16)));
            float ab = __half2float(__ushort_as_half((unsigned short)(ebv[i] >> 16)));
            u32x2 qa = Q2[(int)ca * 64 + lane];
            u32x2 qb = Q2[(int)cb * 64 + lane];
            da0 += __uint_as_float(qa.x << 16);
            da1 += __uint_as_float(qa.y << 16);
            ha0 += aa * __uint_as_float(qa.x & 0xFFFF0000u);
            ha1 += aa * __uint_as_float(qa.y & 0xFFFF0000u);
            db0 += __uint_as_float(qb.x << 16);
            db1 += __uint_as_float(qb.y << 16);
            hb0 += ab * __uint_as_float(qb.x & 0xFFFF0000u);
            hb1 += ab * __uint_as_float(qb.y & 0xFFFF0000u);
        }
    }
    float oa0 = (da0 == 0.f) ? 0.f : ha0 / da0;
    float oa1 = (da1 == 0.f) ? 0.f : ha1 / da1;
    float ob0 = (db0 == 0.f) ? 0.f : hb0 / db0;
    float ob1 = (db1 == 0.f) ? 0.f : hb1 / db1;
    Hnb[ra * 64 + lane] = bf16_rne(oa0) | (bf16_rne(oa1) << 16);
    Hnb[rb * 64 + lane] = bf16_rne(ob0) | (bf16_rne(ob1) << 16);
}

// ---------- out = elu(Hn @ W) via MFMA bf16 ----------
__global__ __launch_bounds__(256)
void k_gemm(const unsigned* __restrict__ Hnb, const float* __restrict__ W,
            float* __restrict__ out) {
    __shared__ short Wb[128 * 128];  // 32KB: [((t*4+ks)*64 + l)*8 + j]
    int tid = threadIdx.x;

#pragma unroll
    for (int i = 0; i < 8; ++i) {
        int c = tid + i * 256;            // 0..2047
        int nl = c & 15;
        int t8 = (c >> 4) & 7;
        int ks = (c >> 7) & 3;
        int lh = (c >> 9) & 3;
        int l = nl | (lh << 4);
        int n = t8 * 16 + nl;
        int k0 = ks * 32 + lh * 8;
        short v[8];
#pragma unroll
        for (int j = 0; j < 8; ++j)
            v[j] = (short)bf16_rne(W[(k0 + j) * 128 + n]);
        *reinterpret_cast<bf16x8*>(&Wb[((t8 * 4 + ks) * 64 + l) * 8]) =
            *reinterpret_cast<bf16x8*>(v);
    }
    __syncthreads();

    int wave = tid >> 6, lane = tid & 63;
    int r0 = blockIdx.x * 64 + wave * 16;
    int mrow = lane & 15;
    int kg = lane >> 4;
    int arow = min(r0 + mrow, NN - 1);
    const u32x4* H4 = reinterpret_cast<const u32x4*>(Hnb);

    bf16x8 a[4];
#pragma unroll
    for (int ks = 0; ks < 4; ++ks) {
        u32x4 v = H4[(size_t)arow * 16 + ks * 4 + kg];
        a[ks] = *reinterpret_cast<bf16x8*>(&v);
    }

    f32x4 acc[8];
#pragma unroll
    for (int t8 = 0; t8 < 8; ++t8) acc[t8] = (f32x4){0.f, 0.f, 0.f, 0.f};

#pragma unroll
    for (int t8 = 0; t8 < 8; ++t8) {
#pragma unroll
        for (int ks = 0; ks < 4; ++ks) {
            bf16x8 b = *reinterpret_cast<const bf16x8*>(
                &Wb[((t8 * 4 + ks) * 64 + lane) * 8]);
            acc[t8] = __builtin_amdgcn_mfma_f32_16x16x32_bf16(a[ks], b, acc[t8], 0, 0, 0);
        }
    }

    // C/D layout: col = lane&15, row = (lane>>4)*4 + reg  [m89-verified]
    int colb = lane & 15;
    int rsub = (lane >> 4) * 4;
#pragma unroll
    for (int t8 = 0; t8 < 8; ++t8) {
#pragma unroll
        for (int rg = 0; rg < 4; ++rg) {
            int row = r0 + rsub + rg;
            if (row < NN) {
                float v = acc[t8][rg];
                float o = (v > 0.f) ? v : (__expf(v) - 1.0f);
                __builtin_nontemporal_store(o, &out[(size_t)row * 128 + t8 * 16 + colb]);
            }
        }
    }
}

// ================= fallback (atomic scatter) if ws is small =================
__global__ void k_init_fb(float* __restrict__ denomH, int* __restrict__ flags) {
    int i = blockIdx.x * blockDim.x + threadIdx.x;
    const int total4 = (2 * NF) / 4;
    if (i < total4)
        reinterpret_cast<float4*>(denomH)[i] = make_float4(0.f, 0.f, 0.f, 0.f);
    if (i < NN) flags[i] = 0;
}

__global__ void k_flags_fb(const int* __restrict__ ids, int* __restrict__ flags) {
    int i = blockIdx.x * blockDim.x + threadIdx.x;
    if (i < NT) flags[ids[i]] = 1;
}

__global__ __launch_bounds__(256)
void k_edge_fb(const int* __restrict__ rows, const int* __restrict__ cols,
               const float* __restrict__ adj, const float* __restrict__ M,
               const int* __restrict__ flags, const float* __restrict__ x,
               float* __restrict__ denom, float* __restrict__ H) {
    int t = blockIdx.x * blockDim.x + threadIdx.x;
    int e = t >> 6;
    int lane = t & 63;
    if (e >= NE) return;
    int r = rows[e], c = cols[e];
    float a = adj[e];
#pragma unroll
    for (int i = 0; i < 2; ++i) {
        int f = lane + i * 64;
        float m = M[c * FF + f];
        float me = flags[c] ? 1.0f : 1.0f / (1.0f + __expf(-m));
        float xv = x[c * FF + f];
        unsafeAtomicAdd(&denom[r * FF + f], me);
        unsafeAtomicAdd(&H[r * FF + f], a * me * xv);
    }
}

__global__ __launch_bounds__(256)
void k_norm_fb(const float* __restrict__ H, const float* __restrict__ denom,
               float* __restrict__ Hn) {
    int i = blockIdx.x * blockDim.x + threadIdx.x;
    if (i >= NF) return;
    float d = denom[i];
    Hn[i] = (d == 0.f) ? 0.f : H[i] / d;
}

__global__ __launch_bounds__(256)
void k_gemm_fb(const float* __restrict__ Hn, const float* __restrict__ W,
               float* __restrict__ out) {
    __shared__ float Ws[128][128];
    __shared__ float Hs[32][128];
    int tid = threadIdx.x;
    const float4* W4 = reinterpret_cast<const float4*>(W);
    float4* Ws4 = reinterpret_cast<float4*>(&Ws[0][0]);
#pragma unroll
    for (int i = 0; i < 16; ++i) Ws4[tid + i * 256] = W4[tid + i * 256];
    int r0 = blockIdx.x * 32;
    const float4* H4 = reinterpret_cast<const float4*>(Hn);
    float4* Hs4 = reinterpret_cast<float4*>(&Hs[0][0]);
#pragma unroll
    for (int i = 0; i < 4; ++i) {
        int m = tid + i * 256;
        int r = m >> 5, k4 = m & 31;
        int row = r0 + r;
        Hs4[m] = (row < NN) ? H4[row * 32 + k4] : make_float4(0.f, 0.f, 0.f, 0.f);
    }
    __syncthreads();
    int c = tid & 127, rg = tid >> 7;
    float acc[16];
#pragma unroll
    for (int i = 0; i < 16; ++i) acc[i] = 0.f;
    for (int k = 0; k < 128; k += 4) {
        float w0 = Ws[k][c], w1 = Ws[k + 1][c], w2 = Ws[k + 2][c], w3 = Ws[k + 3][c];
#pragma unroll
        for (int i = 0; i < 16; ++i) {
            float4 h = *reinterpret_cast<const float4*>(&Hs[rg * 16 + i][k]);
            acc[i] += h.x * w0 + h.y * w1 + h.z * w2 + h.w * w3;
        }
    }
#pragma unroll
    for (int i = 0; i < 16; ++i) {
        int row = r0 + rg * 16 + i;
        if (row < NN) {
            float v = acc[i];
            out[row * 128 + c] = (v > 0.f) ? v : (__expf(v) - 1.0f);
        }
    }
}

extern "C" void kernel_launch(void* const* d_in, const int* in_sizes, int n_in,
                              void* d_out, int out_size, void* d_ws, size_t ws_size,
                              hipStream_t stream) {
    const float* x     = (const float*)d_in[0];
    const int*   erows = (const int*)d_in[1];
    const int*   ecols = (const int*)d_in[2];
    const float* adj   = (const float*)d_in[3];
    const int*   train = (const int*)d_in[4];
    const float* M     = (const float*)d_in[5];
    const float* W     = (const float*)d_in[6];
    float* out = (float*)d_out;
    float* ws  = (float*)d_ws;

    // ws layout (4-byte units):
    // [Q: NF+FF][union: Hnb (NF/2) / ebuf (NBKT*BCAP*2)][gedges: NE]
    // [offsets: NN+1][gcur: 256]
    const size_t UNI = ((size_t)NBKT * BCAP * 2 > (size_t)NF / 2)
                           ? (size_t)NBKT * BCAP * 2 : (size_t)NF / 2;
    size_t fo = 0;
    unsigned* Q   = (unsigned*)(ws + fo); fo += NF + FF;
    unsigned* Hnb = (unsigned*)(ws + fo);
    unsigned long long* ebuf = (unsigned long long*)(ws + fo); fo += UNI;
    unsigned* gedges = (unsigned*)(ws + fo); fo += NE;
    int* offsets  = (int*)(ws + fo); fo += NN + 1;
    int* gcur     = (int*)(ws + fo); fo += 256;
    const size_t need = fo * 4;  // ~41.8 MB

    if (ws_size >= need) {
        const int trn_blocks = (TRN_THREADS + 1023) / 1024;  // 157
        k_pack<<<(NF / 4 + FF / 4 + 255) / 256, 256, 0, stream>>>(M, x, Q, gcur);
        k_pass1<<<P1BLK + trn_blocks, 1024, 0, stream>>>(
            erows, ecols, adj, train, x, Q, gcur, ebuf);
        k_pass2<<<NBKT, 1024, 0, stream>>>(gcur, ebuf, gedges, offsets);
        k_gather<<<((NN / 2) * 64 + 255) / 256, 256, 0, stream>>>(offsets, gedges, Q, Hnb);
        k_gemm<<<(NN + 63) / 64, 256, 0, stream>>>(Hnb, W, out);
    } else {
        float* denom = ws;
        float* H     = ws + NF;
        int* flags_fb = (int*)(ws + 2 * (size_t)NF);
        k_init_fb<<<(2 * NF / 4 + 255) / 256, 256, 0, stream>>>(denom, flags_fb);
        k_flags_fb<<<(NT + 255) / 256, 256, 0, stream>>>(train, flags_fb);
        k_edge_fb<<<((size_t)NE * 64 + 255) / 256, 256, 0, stream>>>(
            erows, ecols, adj, M, flags_fb, x, denom, H);
        k_norm_fb<<<(NF + 255) / 256, 256, 0, stream>>>(H, denom, denom);
        k_gemm_fb<<<(NN + 31) / 32, 256, 0, stream>>>(denom, W, out);
    }
}